// Round 12
// baseline (42.944 us; speedup 1.0000x reference)
//
#include <hip/hip_runtime.h>

#define H_DIM 3072
#define W_DIM 3072

// 4B-aligned vector types: tap base addrs ((r*W+c)*3 floats) are only 4B-aligned.
typedef float f32x4 __attribute__((ext_vector_type(4)));
typedef float f32x2 __attribute__((ext_vector_type(2)));
typedef f32x4 __attribute__((aligned(4))) f32x4u;
typedef f32x2 __attribute__((aligned(4))) f32x2u;

__global__ __launch_bounds__(256) void rotation_kernel(
    const float* __restrict__ img,     // (H, W, 3) f32
    const float* __restrict__ fv,      // (1,) f32
    float* __restrict__ out)           // (H, W, 3) f32
{
    // 4 px/thread at 64-column stride: every load instruction keeps the
    // dense 12B lane stride (R10's win), but 16 loads are in flight per
    // thread instead of 4 (R5's batching, without its 48B-stride mistake).
    const int lane = threadIdx.x;              // 0..63 = consecutive columns
    const int ty   = threadIdx.y;              // 0..3
    const int c0   = blockIdx.x * 256 + lane;  // groups at c0 + 64*g
    const int r    = blockIdx.y * 4 + ty;

    // theta in [0, 0.349] rad; HW trig absmax identical to libm (R5 evidence)
    const float theta = fv[0] * 20.0f * (3.14159265358979323846f / 180.0f);
    const float ct = __cosf(theta);
    const float st = __sinf(theta);

    const float o_r = (float)H_DIM / 2.0f + 0.5f;   // 1536.5
    const float o_c = (float)W_DIM / 2.0f + 0.5f;

    const float drr = (float)r - o_r;
    const float base_r = ct * drr + o_r;   // src_r = base_r - st*(c - o_c)
    const float base_c = st * drr + o_c;   // src_c = base_c + ct*(c - o_c)

    // ---- phase 1: coords + tap addresses for all 4 column-groups ----
    float wrv[4], wcv[4];
    const float* rp0[4];
    const float* rp1[4];
    #pragma unroll
    for (int g = 0; g < 4; ++g) {
        const float dc = (float)(c0 + 64 * g) - o_c;
        float src_r = base_r - st * dc;
        float src_c = base_c + ct * dc;
        src_r = fminf(fmaxf(src_r, 0.0f), (float)(H_DIM - 1));
        src_c = fminf(fmaxf(src_c, 0.0f), (float)(W_DIM - 1));

        // Window-base trick: base = min(floor, dim-2), weight = src - base.
        // Interior: identical to reference. Clamped edge: weight == 1.0
        // exactly, blend selects the far tap == edge px (fill_mode=nearest).
        const int rb = min((int)src_r, H_DIM - 2);
        const int cb = min((int)src_c, W_DIM - 2);
        wrv[g] = src_r - (float)rb;
        wcv[g] = src_c - (float)cb;
        rp0[g] = img + (size_t)(rb * W_DIM + cb) * 3;
        rp1[g] = rp0[g] + (size_t)W_DIM * 3;
    }

    // ---- phase 2: issue all 16 tap loads back-to-back (MLP) ----
    f32x4u A0[4], A1[4];
    f32x2u B0[4], B1[4];
    #pragma unroll
    for (int g = 0; g < 4; ++g) {
        A0[g] = *(const f32x4u*)rp0[g];
        B0[g] = *(const f32x2u*)(rp0[g] + 4);
        A1[g] = *(const f32x4u*)rp1[g];
        B1[g] = *(const f32x2u*)(rp1[g] + 4);
    }

    // ---- phase 3: blend + store per group (stores don't block) ----
    #pragma unroll
    for (int g = 0; g < 4; ++g) {
        const float q0[6] = {A0[g][0], A0[g][1], A0[g][2], A0[g][3], B0[g][0], B0[g][1]};
        const float q1[6] = {A1[g][0], A1[g][1], A1[g][2], A1[g][3], B1[g][0], B1[g][1]};
        const float wr = wrv[g], wc = wcv[g];
        float res[3];
        #pragma unroll
        for (int ch = 0; ch < 3; ++ch) {
            const float row0 = q0[ch] + wc * (q0[3 + ch] - q0[ch]);
            const float row1 = q1[ch] + wc * (q1[3 + ch] - q1[ch]);
            res[ch] = row0 + wr * (row1 - row0);
        }
        // 12B/px, wave-contiguous 768B per group (merges to dwordx3)
        float* o = out + ((size_t)r * W_DIM + (c0 + 64 * g)) * 3;
        o[0] = res[0];
        o[1] = res[1];
        o[2] = res[2];
    }
}

extern "C" void kernel_launch(void* const* d_in, const int* in_sizes, int n_in,
                              void* d_out, int out_size, void* d_ws, size_t ws_size,
                              hipStream_t stream) {
    const float* img = (const float*)d_in[0];
    const float* fv  = (const float*)d_in[1];
    float* out = (float*)d_out;

    dim3 block(64, 4, 1);
    dim3 grid(W_DIM / 256, H_DIM / 4, 1);
    rotation_kernel<<<grid, block, 0, stream>>>(img, fv, out);
}

// Round 13
// 42.860 us; speedup vs baseline: 1.0020x; 1.0020x over previous
//
#include <hip/hip_runtime.h>

#define H_DIM 3072
#define W_DIM 3072

// 4B-aligned vector types: tap base addrs ((r*W+c)*3 floats) are only 4B-aligned.
typedef float f32x4 __attribute__((ext_vector_type(4)));
typedef float f32x2 __attribute__((ext_vector_type(2)));
typedef f32x4 __attribute__((aligned(4))) f32x4u;
typedef f32x2 __attribute__((aligned(4))) f32x2u;

__global__ __launch_bounds__(256) void rotation_kernel(
    const float* __restrict__ img,     // (H, W, 3) f32
    const float* __restrict__ fv,      // (1,) f32
    float* __restrict__ out)           // (H, W, 3) f32
{
    // 4 px/thread at 64-column stride: every load instruction keeps the
    // dense 12B lane stride (R10's win), but 16 loads are in flight per
    // thread instead of 4 (R5's batching, without its 48B-stride mistake).
    const int lane = threadIdx.x;              // 0..63 = consecutive columns
    const int ty   = threadIdx.y;              // 0..3
    const int c0   = blockIdx.x * 256 + lane;  // groups at c0 + 64*g
    const int r    = blockIdx.y * 4 + ty;

    // theta in [0, 0.349] rad; HW trig absmax identical to libm (R5 evidence)
    const float theta = fv[0] * 20.0f * (3.14159265358979323846f / 180.0f);
    const float ct = __cosf(theta);
    const float st = __sinf(theta);

    const float o_r = (float)H_DIM / 2.0f + 0.5f;   // 1536.5
    const float o_c = (float)W_DIM / 2.0f + 0.5f;

    const float drr = (float)r - o_r;
    const float base_r = ct * drr + o_r;   // src_r = base_r - st*(c - o_c)
    const float base_c = st * drr + o_c;   // src_c = base_c + ct*(c - o_c)

    // ---- phase 1: coords + tap addresses for all 4 column-groups ----
    float wrv[4], wcv[4];
    const float* rp0[4];
    const float* rp1[4];
    #pragma unroll
    for (int g = 0; g < 4; ++g) {
        const float dc = (float)(c0 + 64 * g) - o_c;
        float src_r = base_r - st * dc;
        float src_c = base_c + ct * dc;
        src_r = fminf(fmaxf(src_r, 0.0f), (float)(H_DIM - 1));
        src_c = fminf(fmaxf(src_c, 0.0f), (float)(W_DIM - 1));

        // Window-base trick: base = min(floor, dim-2), weight = src - base.
        // Interior: identical to reference. Clamped edge: weight == 1.0
        // exactly, blend selects the far tap == edge px (fill_mode=nearest).
        const int rb = min((int)src_r, H_DIM - 2);
        const int cb = min((int)src_c, W_DIM - 2);
        wrv[g] = src_r - (float)rb;
        wcv[g] = src_c - (float)cb;
        rp0[g] = img + (size_t)(rb * W_DIM + cb) * 3;
        rp1[g] = rp0[g] + (size_t)W_DIM * 3;
    }

    // ---- phase 2: issue all 16 tap loads back-to-back (MLP) ----
    f32x4u A0[4], A1[4];
    f32x2u B0[4], B1[4];
    #pragma unroll
    for (int g = 0; g < 4; ++g) {
        A0[g] = *(const f32x4u*)rp0[g];
        B0[g] = *(const f32x2u*)(rp0[g] + 4);
        A1[g] = *(const f32x4u*)rp1[g];
        B1[g] = *(const f32x2u*)(rp1[g] + 4);
    }

    // ---- phase 3: blend + store per group (stores don't block) ----
    #pragma unroll
    for (int g = 0; g < 4; ++g) {
        const float q0[6] = {A0[g][0], A0[g][1], A0[g][2], A0[g][3], B0[g][0], B0[g][1]};
        const float q1[6] = {A1[g][0], A1[g][1], A1[g][2], A1[g][3], B1[g][0], B1[g][1]};
        const float wr = wrv[g], wc = wcv[g];
        float res[3];
        #pragma unroll
        for (int ch = 0; ch < 3; ++ch) {
            const float row0 = q0[ch] + wc * (q0[3 + ch] - q0[ch]);
            const float row1 = q1[ch] + wc * (q1[3 + ch] - q1[ch]);
            res[ch] = row0 + wr * (row1 - row0);
        }
        // 12B/px, wave-contiguous 768B per group (merges to dwordx3)
        float* o = out + ((size_t)r * W_DIM + (c0 + 64 * g)) * 3;
        o[0] = res[0];
        o[1] = res[1];
        o[2] = res[2];
    }
}

extern "C" void kernel_launch(void* const* d_in, const int* in_sizes, int n_in,
                              void* d_out, int out_size, void* d_ws, size_t ws_size,
                              hipStream_t stream) {
    const float* img = (const float*)d_in[0];
    const float* fv  = (const float*)d_in[1];
    float* out = (float*)d_out;

    dim3 block(64, 4, 1);
    dim3 grid(W_DIM / 256, H_DIM / 4, 1);
    rotation_kernel<<<grid, block, 0, stream>>>(img, fv, out);
}

// Round 14
// 40.012 us; speedup vs baseline: 1.0733x; 1.0712x over previous
//
#include <hip/hip_runtime.h>

#define H_DIM 3072
#define W_DIM 3072

// 4B-aligned vector types: tap base addrs ((r*W+c)*3 floats) are only 4B-aligned.
typedef float f32x4 __attribute__((ext_vector_type(4)));
typedef float f32x2 __attribute__((ext_vector_type(2)));
typedef f32x4 __attribute__((aligned(4))) f32x4u;
typedef f32x2 __attribute__((aligned(4))) f32x2u;

__global__ __launch_bounds__(256) void rotation_kernel(
    const float* __restrict__ img,     // (H, W, 3) f32
    const float* __restrict__ fv,      // (1,) f32
    float* __restrict__ out)           // (H, W, 3) f32
{
    // 1 px/thread; wave = 64 CONSECUTIVE columns -> tap lane-stride 12B.
    // Measured best (R10: 40.0us): minimal distinct cache lines per
    // gather instruction; batching (R13) and swizzling (R11) both regress.
    const int c = blockIdx.x * 64 + threadIdx.x;
    const int r = blockIdx.y * 4 + threadIdx.y;

    // theta in [0, 0.349] rad; HW trig absmax identical to libm (R5 evidence)
    const float theta = fv[0] * 20.0f * (3.14159265358979323846f / 180.0f);
    const float ct = __cosf(theta);
    const float st = __sinf(theta);

    const float o_r = (float)H_DIM / 2.0f + 0.5f;   // 1536.5
    const float o_c = (float)W_DIM / 2.0f + 0.5f;

    float src_r = ct * ((float)r - o_r) - st * ((float)c - o_c) + o_r;
    float src_c = st * ((float)r - o_r) + ct * ((float)c - o_c) + o_c;
    src_r = fminf(fmaxf(src_r, 0.0f), (float)(H_DIM - 1));
    src_c = fminf(fmaxf(src_c, 0.0f), (float)(W_DIM - 1));

    // Window-base trick: base = min(floor, dim-2), weight = src - base.
    // Interior: identical to reference. At a clamped edge (floor == dim-1,
    // ref weight 0): base shifts back one, weight becomes exactly 1.0, and
    // the blend selects the far tap = edge pixel (fill_mode='nearest').
    const int rb = min((int)src_r, H_DIM - 2);   // src_r >= 0 -> (int) == floor
    const int cb = min((int)src_c, W_DIM - 2);
    const float wr = src_r - (float)rb;
    const float wc = src_c - (float)cb;

    const float* rp0 = img + (size_t)(rb * W_DIM + cb) * 3;
    const float* rp1 = rp0 + (size_t)W_DIM * 3;

    // 6 consecutive floats per tap row: x4 + x2 (minimum for interleaved RGB)
    const f32x4u A0 = *(const f32x4u*)rp0;
    const f32x2u B0 = *(const f32x2u*)(rp0 + 4);
    const f32x4u A1 = *(const f32x4u*)rp1;
    const f32x2u B1 = *(const f32x2u*)(rp1 + 4);

    const float q0[6] = {A0[0], A0[1], A0[2], A0[3], B0[0], B0[1]};
    const float q1[6] = {A1[0], A1[1], A1[2], A1[3], B1[0], B1[1]};

    float res[3];
    #pragma unroll
    for (int ch = 0; ch < 3; ++ch) {
        const float row0 = q0[ch] + wc * (q0[3 + ch] - q0[ch]);
        const float row1 = q1[ch] + wc * (q1[3 + ch] - q1[ch]);
        res[ch] = row0 + wr * (row1 - row0);
    }

    // 12B/px, wave-contiguous 768B: compiler merges stores
    float* o = out + ((size_t)r * W_DIM + c) * 3;
    o[0] = res[0];
    o[1] = res[1];
    o[2] = res[2];
}

extern "C" void kernel_launch(void* const* d_in, const int* in_sizes, int n_in,
                              void* d_out, int out_size, void* d_ws, size_t ws_size,
                              hipStream_t stream) {
    const float* img = (const float*)d_in[0];
    const float* fv  = (const float*)d_in[1];
    float* out = (float*)d_out;

    dim3 block(64, 4, 1);
    dim3 grid(W_DIM / 64, H_DIM / 4, 1);
    rotation_kernel<<<grid, block, 0, stream>>>(img, fv, out);
}